// Round 4
// baseline (175.414 us; speedup 1.0000x reference)
//
#include <hip/hip_runtime.h>
#include <math.h>

#define D 128
#define H 64
#define W 100
#define R 20
#define NB 256
#define NDOC_UI (NB * R)   // 5120

// e^(2x) identity tanh: exact saturation at +-1 via inf/0 in rcp.
__device__ __forceinline__ float fast_tanh(float x) {
    float u = __expf(2.0f * x);
    return 1.0f - 2.0f * __builtin_amdgcn_rcpf(1.0f + u);
}
__device__ __forceinline__ float fast_exp_tanh(float x) {
    return __expf(fast_tanh(x));
}

// ---------------- Kernel A: tanh-self-attention doc embedding ----------------
// One 32-lane group per doc, 8 docs per 256-thread block. Barrier-free,
// LDS-free: word ids in 4 VGPRs (ds_bpermute broadcast), row slice float4 per
// lane, score via 5 xor-shuffles (each wave-instr serves 2 docs), softmax
// weights & weighted sum fully register-resident, coalesced dwordx4 output.
__global__ __launch_bounds__(256, 7) void doc_embed_kernel(
    const int* __restrict__ user_w, const int* __restrict__ item_w,
    const int* __restrict__ query_w,
    const float* __restrict__ emb, const float* __restrict__ w_self,
    const float* __restrict__ b_self,
    float* __restrict__ user_emb, float* __restrict__ item_emb,
    float* __restrict__ q_emb)
{
    int tid    = threadIdx.x;
    int lane32 = tid & 31;
    int grp    = tid >> 5;                 // 0..7
    int doc    = blockIdx.x * 8 + grp;     // 10496 = 1312*8 exactly

    const int* wp; float* outp;
    if (doc < NDOC_UI)        { wp = user_w + doc * W;               outp = user_emb + doc * D; }
    else if (doc < 2*NDOC_UI) { int t = doc - NDOC_UI;   wp = item_w  + t * W; outp = item_emb + t * D; }
    else                      { int t = doc - 2*NDOC_UI; wp = query_w + t * W; outp = q_emb    + t * D; }

    // Word ids: wreg[k] lane l holds words[k*32+l] (clamped dup for tail).
    int wreg[4];
    #pragma unroll
    for (int k = 0; k < 4; ++k) {
        int idx = k * 32 + lane32;
        wreg[k] = wp[idx > W - 1 ? W - 1 : idx];
    }

    float4 ws4 = ((const float4*)w_self)[lane32];
    float  bs  = b_self[0];
    const float4* emb4 = (const float4*)emb;

    int permbase = (tid & 32) * 4;         // bpermute byte base of my 32-half

    float4 acc  = make_float4(0.f, 0.f, 0.f, 0.f);
    float  esum = 0.f;

    #pragma unroll
    for (int c = 0; c < 10; ++c) {
        int word[10];
        #pragma unroll
        for (int j = 0; j < 10; ++j) {
            int w = c * 10 + j;
            word[j] = __builtin_amdgcn_ds_bpermute(permbase | ((w & 31) * 4),
                                                   wreg[w >> 5]);
        }
        float4 v[10];
        #pragma unroll
        for (int j = 0; j < 10; ++j)
            v[j] = emb4[(size_t)word[j] * 32 + lane32];

        #pragma unroll
        for (int j = 0; j < 10; ++j) {
            float p = v[j].x * ws4.x + v[j].y * ws4.y + v[j].z * ws4.z + v[j].w * ws4.w;
            p += __shfl_xor(p, 16, 64);
            p += __shfl_xor(p, 8, 64);
            p += __shfl_xor(p, 4, 64);
            p += __shfl_xor(p, 2, 64);
            p += __shfl_xor(p, 1, 64);
            float e = fast_exp_tanh(p + bs);
            esum += e;
            acc.x += e * v[j].x;
            acc.y += e * v[j].y;
            acc.z += e * v[j].z;
            acc.w += e * v[j].w;
        }
    }

    float inv = 1.0f / esum;
    acc.x *= inv; acc.y *= inv; acc.z *= inv; acc.w *= inv;
    ((float4*)outp)[lane32] = acc;
}

// ---------------- Kernel B: pv[b,d] = sum_h tanh(q@Wq+bq)[b,d*64+h]*w_red[h] -
// w_red folded into GEMM epilogue (linear), so the 8 MB pq tensor never exists.
__global__ __launch_bounds__(256) void pv_kernel(
    const float* __restrict__ q_emb, const float* __restrict__ Wq,
    const float* __restrict__ bq, const float* __restrict__ w_red,
    float* __restrict__ pv)
{
    __shared__ __align__(16) float qs[64 * 132];    // 33.8 KB
    __shared__ __align__(16) float Wb[128 * 68];    // 34.8 KB

    int dd  = blockIdx.x;          // 0..127
    int m0g = blockIdx.y * 64;     // row offset
    int tid = threadIdx.x;

    {
        int rrow = tid >> 4;       // 0..15
        int f4   = tid & 15;       // 0..15
        #pragma unroll
        for (int pass = 0; pass < 4; ++pass) {
            int m = pass * 16 + rrow;
            float4 vq = ((const float4*)q_emb)[(m0g + m) * 32 + f4];
            *(float4*)&qs[m * 132 + f4 * 4] = vq;
        }
        #pragma unroll
        for (int pass = 0; pass < 8; ++pass) {
            int k = pass * 16 + rrow;
            float4 vw = ((const float4*)Wq)[k * 2048 + dd * 16 + f4];
            *(float4*)&Wb[k * 68 + f4 * 4] = vw;
        }
    }
    __syncthreads();

    int nthr = tid & 7;            // n0 = nthr*8
    int mthr = tid >> 3;           // m0 = mthr*2
    int n0 = nthr * 8;
    int m0 = mthr * 2;

    float acc[2][8];
    #pragma unroll
    for (int i = 0; i < 2; ++i)
        #pragma unroll
        for (int j = 0; j < 8; ++j) acc[i][j] = 0.f;

    for (int k = 0; k < 128; ++k) {
        float4 b0 = *(const float4*)&Wb[k * 68 + n0];
        float4 b1 = *(const float4*)&Wb[k * 68 + n0 + 4];
        float a0 = qs[(m0 + 0) * 132 + k];
        float a1 = qs[(m0 + 1) * 132 + k];
        float bv[8] = {b0.x, b0.y, b0.z, b0.w, b1.x, b1.y, b1.z, b1.w};
        #pragma unroll
        for (int j = 0; j < 8; ++j) {
            acc[0][j] += a0 * bv[j];
            acc[1][j] += a1 * bv[j];
        }
    }

    float4 bqa = ((const float4*)bq)[dd * 16 + nthr * 2];
    float4 bqb = ((const float4*)bq)[dd * 16 + nthr * 2 + 1];
    float4 wra = ((const float4*)w_red)[nthr * 2];
    float4 wrb = ((const float4*)w_red)[nthr * 2 + 1];
    float bqv[8] = {bqa.x, bqa.y, bqa.z, bqa.w, bqb.x, bqb.y, bqb.z, bqb.w};
    float wrv[8] = {wra.x, wra.y, wra.z, wra.w, wrb.x, wrb.y, wrb.z, wrb.w};

    #pragma unroll
    for (int i = 0; i < 2; ++i) {
        float s = 0.f;
        #pragma unroll
        for (int j = 0; j < 8; ++j)
            s += fast_tanh(acc[i][j] + bqv[j]) * wrv[j];
        s += __shfl_xor(s, 1, 64);
        s += __shfl_xor(s, 2, 64);
        s += __shfl_xor(s, 4, 64);
        if (nthr == 0) pv[(m0g + m0 + i) * 128 + dd] = s;
    }
}

// ---------------- Kernel C: review attention + output ------------------------
__global__ __launch_bounds__(256) void attn_kernel(
    const float* __restrict__ user_emb, const float* __restrict__ item_emb,
    const float* __restrict__ q_emb, const float* __restrict__ pv,
    const float* __restrict__ pf, float* __restrict__ out)
{
    __shared__ float rev[R * 129];
    __shared__ float pvl[D];
    __shared__ float sc[R];

    int b   = blockIdx.x;
    int set = blockIdx.y;
    const float* revg = (set == 0 ? user_emb : item_emb) + b * R * D;
    int tid = threadIdx.x;

    for (int idx = tid; idx < R * D; idx += 256)
        rev[(idx >> 7) * 129 + (idx & 127)] = revg[idx];
    if (tid < D) pvl[tid] = pv[b * D + tid];
    __syncthreads();

    if (tid < R) {
        float s = 0.f;
        const float* row = &rev[tid * 129];
        #pragma unroll 16
        for (int k = 0; k < D; ++k) s += row[k] * pvl[k];
        sc[tid] = s;
    }
    __syncthreads();

    float m = -1e30f;
    for (int r = 0; r < R; ++r) m = fmaxf(m, sc[r]);
    float sum = 0.f;
    for (int r = 0; r < R; ++r) sum += __expf(sc[r] - m);
    float inv = 1.f / sum;

    if (tid < D) {
        float acc = 0.f;
        for (int r = 0; r < R; ++r)
            acc += __expf(sc[r] - m) * inv * rev[r * 129 + tid];
        if (set == 0) {
            acc += pf[0] * q_emb[b * D + tid];
            out[b * D + tid] = acc;                 // personalized
        } else {
            out[NB * D + b * D + tid] = acc;        // item_entity
        }
    }
}

extern "C" void kernel_launch(void* const* d_in, const int* in_sizes, int n_in,
                              void* d_out, int out_size, void* d_ws, size_t ws_size,
                              hipStream_t stream) {
    const int*   user_w  = (const int*)d_in[0];
    const int*   item_w  = (const int*)d_in[1];
    const int*   query_w = (const int*)d_in[2];
    const float* emb     = (const float*)d_in[3];
    const float* w_self  = (const float*)d_in[4];
    const float* b_self  = (const float*)d_in[5];
    const float* Wq      = (const float*)d_in[6];
    const float* bq      = (const float*)d_in[7];
    const float* w_red   = (const float*)d_in[8];
    const float* pf      = (const float*)d_in[9];

    float* ws       = (float*)d_ws;
    float* user_emb = ws;                         // 5120*128
    float* item_emb = user_emb + NDOC_UI * D;     // 5120*128
    float* q_emb    = item_emb + NDOC_UI * D;     // 256*128
    float* pv       = q_emb    + NB * D;          // 256*128
    float* out      = (float*)d_out;

    doc_embed_kernel<<<(2 * NDOC_UI + NB) / 8, 256, 0, stream>>>(
        user_w, item_w, query_w, emb, w_self, b_self, user_emb, item_emb, q_emb);
    pv_kernel<<<dim3(128, 4), 256, 0, stream>>>(q_emb, Wq, bq, w_red, pv);
    attn_kernel<<<dim3(NB, 2), 256, 0, stream>>>(user_emb, item_emb, q_emb, pv, pf, out);
}

// Round 6
// 151.855 us; speedup vs baseline: 1.1551x; 1.1551x over previous
//
#include <hip/hip_runtime.h>
#include <math.h>

#define D 128
#define H 64
#define W 100
#define R 20
#define NB 256
#define NDOC_UI (NB * R)   // 5120
#define VOCAB 50000

// e^(2x) identity tanh: exact saturation at +-1 via inf/0 in rcp.
__device__ __forceinline__ float fast_tanh(float x) {
    float u = __expf(2.0f * x);
    return 1.0f - 2.0f * __builtin_amdgcn_rcpf(1.0f + u);
}
__device__ __forceinline__ float fast_exp_tanh(float x) {
    return __expf(fast_tanh(x));
}

// fp32 -> bf16 round-to-nearest-even
__device__ __forceinline__ unsigned short f2bf(float f) {
    unsigned int b = __float_as_uint(f);
    b += 0x7fffu + ((b >> 16) & 1u);
    return (unsigned short)(b >> 16);
}

// ---------------- Kernel 0 (fast path): vocab prep ---------------------------
// Score e = exp(tanh(emb_row . w_self + b)) is doc-independent. Precompute per
// vocab row; store PRE-SCALED row e*emb as bf16 (256 B vs 512 B) + evocab[v]=e.
__global__ __launch_bounds__(256) void vocab_prep_kernel(
    const float* __restrict__ emb, const float* __restrict__ w_self,
    const float* __restrict__ b_self,
    ushort* __restrict__ emb_bf, float* __restrict__ evocab)
{
    int tid = threadIdx.x, lane32 = tid & 31, grp = tid >> 5;
    int row = blockIdx.x * 8 + grp;            // 6250 blocks, exact
    float4 v   = ((const float4*)emb)[row * 32 + lane32];
    float4 ws4 = ((const float4*)w_self)[lane32];
    float p = v.x * ws4.x + v.y * ws4.y + v.z * ws4.z + v.w * ws4.w;
    p += __shfl_xor(p, 16, 64);
    p += __shfl_xor(p, 8, 64);
    p += __shfl_xor(p, 4, 64);
    p += __shfl_xor(p, 2, 64);
    p += __shfl_xor(p, 1, 64);
    float e = __expf(tanhf(p + b_self[0]));    // precise tanh: only 50K evals
    if (lane32 == 0) evocab[row] = e;
    ushort4 u;
    u.x = f2bf(v.x * e); u.y = f2bf(v.y * e);
    u.z = f2bf(v.z * e); u.w = f2bf(v.w * e);
    ((ushort4*)emb_bf)[row * 32 + lane32] = u;
}

// ---------------- Kernel A (fast path): doc embed = weighted gather-sum ------
// One 32-lane group per doc, 8 docs/block, barrier/LDS-free. Rows pre-scaled
// bf16 (256 B): 16 lanes x 16 B per row -> each dwordx4 covers 2 words.
__global__ __launch_bounds__(256) void doc_embed_bf16_kernel(
    const int* __restrict__ user_w, const int* __restrict__ item_w,
    const int* __restrict__ query_w,
    const ushort* __restrict__ emb_bf, const float* __restrict__ evocab,
    float* __restrict__ user_emb, float* __restrict__ item_emb,
    float* __restrict__ q_emb)
{
    int tid    = threadIdx.x;
    int lane32 = tid & 31;
    int grp    = tid >> 5;
    int doc    = blockIdx.x * 8 + grp;     // 10496 = 1312*8 exactly

    const int* wp; float* outp;
    if (doc < NDOC_UI)        { wp = user_w + doc * W;               outp = user_emb + doc * D; }
    else if (doc < 2*NDOC_UI) { int t = doc - NDOC_UI;   wp = item_w  + t * W; outp = item_emb + t * D; }
    else                      { int t = doc - 2*NDOC_UI; wp = query_w + t * W; outp = q_emb    + t * D; }

    int wreg[4];
    #pragma unroll
    for (int k = 0; k < 4; ++k) {
        int idx = k * 32 + lane32;
        wreg[k] = wp[idx > W - 1 ? W - 1 : idx];
    }

    float ep = 0.f;
    #pragma unroll
    for (int k = 0; k < 4; ++k) {
        float e = evocab[wreg[k]];
        if (k < 3 || lane32 < 4) ep += e;
    }
    ep += __shfl_xor(ep, 16, 64);
    ep += __shfl_xor(ep, 8, 64);
    ep += __shfl_xor(ep, 4, 64);
    ep += __shfl_xor(ep, 2, 64);
    ep += __shfl_xor(ep, 1, 64);
    float inv = 1.f / ep;

    int permbase = (tid & 32) << 2;        // bpermute byte base of my 32-half
    int sub      = lane32 >> 4;            // which word of the pair (0/1)
    int quad     = lane32 & 15;            // 16B slice within the row

    float acc[8];
    #pragma unroll
    for (int j = 0; j < 8; ++j) acc[j] = 0.f;

    const uint4* ebf4 = (const uint4*)emb_bf;

    #pragma unroll
    for (int k = 0; k < 3; ++k) {
        #pragma unroll
        for (int hc = 0; hc < 2; ++hc) {
            int wid[8]; uint4 v[8];
            #pragma unroll
            for (int j = 0; j < 8; ++j) {
                int src = (hc * 8 + j) * 2 + sub;     // 0..31 within section
                wid[j] = __builtin_amdgcn_ds_bpermute(permbase | (src << 2), wreg[k]);
            }
            #pragma unroll
            for (int j = 0; j < 8; ++j)
                v[j] = ebf4[(size_t)(unsigned)wid[j] * 16 + quad];
            #pragma unroll
            for (int j = 0; j < 8; ++j) {
                uint4 x = v[j];
                acc[0] += __uint_as_float(x.x << 16);
                acc[1] += __uint_as_float(x.x & 0xffff0000u);
                acc[2] += __uint_as_float(x.y << 16);
                acc[3] += __uint_as_float(x.y & 0xffff0000u);
                acc[4] += __uint_as_float(x.z << 16);
                acc[5] += __uint_as_float(x.z & 0xffff0000u);
                acc[6] += __uint_as_float(x.w << 16);
                acc[7] += __uint_as_float(x.w & 0xffff0000u);
            }
        }
    }
    {   // Tail: words 96..99
        int wid[2]; uint4 v[2];
        #pragma unroll
        for (int j = 0; j < 2; ++j) {
            int src = j * 2 + sub;
            wid[j] = __builtin_amdgcn_ds_bpermute(permbase | (src << 2), wreg[3]);
        }
        #pragma unroll
        for (int j = 0; j < 2; ++j)
            v[j] = ebf4[(size_t)(unsigned)wid[j] * 16 + quad];
        #pragma unroll
        for (int j = 0; j < 2; ++j) {
            uint4 x = v[j];
            acc[0] += __uint_as_float(x.x << 16);
            acc[1] += __uint_as_float(x.x & 0xffff0000u);
            acc[2] += __uint_as_float(x.y << 16);
            acc[3] += __uint_as_float(x.y & 0xffff0000u);
            acc[4] += __uint_as_float(x.z << 16);
            acc[5] += __uint_as_float(x.z & 0xffff0000u);
            acc[6] += __uint_as_float(x.w << 16);
            acc[7] += __uint_as_float(x.w & 0xffff0000u);
        }
    }

    #pragma unroll
    for (int j = 0; j < 8; ++j) acc[j] += __shfl_xor(acc[j], 16, 64);

    if (lane32 < 16) {
        float4 o0 = make_float4(acc[0]*inv, acc[1]*inv, acc[2]*inv, acc[3]*inv);
        float4 o1 = make_float4(acc[4]*inv, acc[5]*inv, acc[6]*inv, acc[7]*inv);
        ((float4*)outp)[quad * 2]     = o0;
        ((float4*)outp)[quad * 2 + 1] = o1;
    }
}

// ---------------- Kernel A' (fallback, R4-proven): fp32 gather doc embed -----
__global__ __launch_bounds__(256, 7) void doc_embed_fp32_kernel(
    const int* __restrict__ user_w, const int* __restrict__ item_w,
    const int* __restrict__ query_w,
    const float* __restrict__ emb, const float* __restrict__ w_self,
    const float* __restrict__ b_self,
    float* __restrict__ user_emb, float* __restrict__ item_emb,
    float* __restrict__ q_emb)
{
    int tid    = threadIdx.x;
    int lane32 = tid & 31;
    int grp    = tid >> 5;
    int doc    = blockIdx.x * 8 + grp;

    const int* wp; float* outp;
    if (doc < NDOC_UI)        { wp = user_w + doc * W;               outp = user_emb + doc * D; }
    else if (doc < 2*NDOC_UI) { int t = doc - NDOC_UI;   wp = item_w  + t * W; outp = item_emb + t * D; }
    else                      { int t = doc - 2*NDOC_UI; wp = query_w + t * W; outp = q_emb    + t * D; }

    int wreg[4];
    #pragma unroll
    for (int k = 0; k < 4; ++k) {
        int idx = k * 32 + lane32;
        wreg[k] = wp[idx > W - 1 ? W - 1 : idx];
    }

    float4 ws4 = ((const float4*)w_self)[lane32];
    float  bs  = b_self[0];
    const float4* emb4 = (const float4*)emb;
    int permbase = (tid & 32) * 4;

    float4 acc  = make_float4(0.f, 0.f, 0.f, 0.f);
    float  esum = 0.f;

    #pragma unroll
    for (int c = 0; c < 10; ++c) {
        int word[10];
        #pragma unroll
        for (int j = 0; j < 10; ++j) {
            int w = c * 10 + j;
            word[j] = __builtin_amdgcn_ds_bpermute(permbase | ((w & 31) * 4),
                                                   wreg[w >> 5]);
        }
        float4 v[10];
        #pragma unroll
        for (int j = 0; j < 10; ++j)
            v[j] = emb4[(size_t)word[j] * 32 + lane32];

        #pragma unroll
        for (int j = 0; j < 10; ++j) {
            float p = v[j].x * ws4.x + v[j].y * ws4.y + v[j].z * ws4.z + v[j].w * ws4.w;
            p += __shfl_xor(p, 16, 64);
            p += __shfl_xor(p, 8, 64);
            p += __shfl_xor(p, 4, 64);
            p += __shfl_xor(p, 2, 64);
            p += __shfl_xor(p, 1, 64);
            float e = fast_exp_tanh(p + bs);
            esum += e;
            acc.x += e * v[j].x;
            acc.y += e * v[j].y;
            acc.z += e * v[j].z;
            acc.w += e * v[j].w;
        }
    }

    float inv = 1.0f / esum;
    acc.x *= inv; acc.y *= inv; acc.z *= inv; acc.w *= inv;
    ((float4*)outp)[lane32] = acc;
}

// ---------------- Kernel B: pv[b,d] = sum_h tanh(q@Wq+bq)[b,d*64+h]*w_red[h] -
__global__ __launch_bounds__(256) void pv_kernel(
    const float* __restrict__ q_emb, const float* __restrict__ Wq,
    const float* __restrict__ bq, const float* __restrict__ w_red,
    float* __restrict__ pv)
{
    __shared__ __align__(16) float qs[64 * 132];
    __shared__ __align__(16) float Wb[128 * 68];

    int dd  = blockIdx.x;
    int m0g = blockIdx.y * 64;
    int tid = threadIdx.x;

    {
        int rrow = tid >> 4;
        int f4   = tid & 15;
        #pragma unroll
        for (int pass = 0; pass < 4; ++pass) {
            int m = pass * 16 + rrow;
            float4 vq = ((const float4*)q_emb)[(m0g + m) * 32 + f4];
            *(float4*)&qs[m * 132 + f4 * 4] = vq;
        }
        #pragma unroll
        for (int pass = 0; pass < 8; ++pass) {
            int k = pass * 16 + rrow;
            float4 vw = ((const float4*)Wq)[k * 2048 + dd * 16 + f4];
            *(float4*)&Wb[k * 68 + f4 * 4] = vw;
        }
    }
    __syncthreads();

    int nthr = tid & 7;
    int mthr = tid >> 3;
    int n0 = nthr * 8;
    int m0 = mthr * 2;

    float acc[2][8];
    #pragma unroll
    for (int i = 0; i < 2; ++i)
        #pragma unroll
        for (int j = 0; j < 8; ++j) acc[i][j] = 0.f;

    for (int k = 0; k < 128; ++k) {
        float4 b0 = *(const float4*)&Wb[k * 68 + n0];
        float4 b1 = *(const float4*)&Wb[k * 68 + n0 + 4];
        float a0 = qs[(m0 + 0) * 132 + k];
        float a1 = qs[(m0 + 1) * 132 + k];
        float bv[8] = {b0.x, b0.y, b0.z, b0.w, b1.x, b1.y, b1.z, b1.w};
        #pragma unroll
        for (int j = 0; j < 8; ++j) {
            acc[0][j] += a0 * bv[j];
            acc[1][j] += a1 * bv[j];
        }
    }

    float4 bqa = ((const float4*)bq)[dd * 16 + nthr * 2];
    float4 bqb = ((const float4*)bq)[dd * 16 + nthr * 2 + 1];
    float4 wra = ((const float4*)w_red)[nthr * 2];
    float4 wrb = ((const float4*)w_red)[nthr * 2 + 1];
    float bqv[8] = {bqa.x, bqa.y, bqa.z, bqa.w, bqb.x, bqb.y, bqb.z, bqb.w};
    float wrv[8] = {wra.x, wra.y, wra.z, wra.w, wrb.x, wrb.y, wrb.z, wrb.w};

    #pragma unroll
    for (int i = 0; i < 2; ++i) {
        float s = 0.f;
        #pragma unroll
        for (int j = 0; j < 8; ++j)
            s += fast_tanh(acc[i][j] + bqv[j]) * wrv[j];
        s += __shfl_xor(s, 1, 64);
        s += __shfl_xor(s, 2, 64);
        s += __shfl_xor(s, 4, 64);
        if (nthr == 0) pv[(m0g + m0 + i) * 128 + dd] = s;
    }
}

// ---------------- Kernel C: review attention + output ------------------------
__global__ __launch_bounds__(256) void attn_kernel(
    const float* __restrict__ user_emb, const float* __restrict__ item_emb,
    const float* __restrict__ q_emb, const float* __restrict__ pv,
    const float* __restrict__ pf, float* __restrict__ out)
{
    __shared__ float rev[R * 129];
    __shared__ float pvl[D];
    __shared__ float sc[R];

    int b   = blockIdx.x;
    int set = blockIdx.y;
    const float* revg = (set == 0 ? user_emb : item_emb) + b * R * D;
    int tid = threadIdx.x;

    for (int idx = tid; idx < R * D; idx += 256)
        rev[(idx >> 7) * 129 + (idx & 127)] = revg[idx];
    if (tid < D) pvl[tid] = pv[b * D + tid];
    __syncthreads();

    if (tid < R) {
        float s = 0.f;
        const float* row = &rev[tid * 129];
        #pragma unroll 16
        for (int k = 0; k < D; ++k) s += row[k] * pvl[k];
        sc[tid] = s;
    }
    __syncthreads();

    float m = -1e30f;
    for (int r = 0; r < R; ++r) m = fmaxf(m, sc[r]);
    float sum = 0.f;
    for (int r = 0; r < R; ++r) sum += __expf(sc[r] - m);
    float inv = 1.f / sum;

    if (tid < D) {
        float acc = 0.f;
        for (int r = 0; r < R; ++r)
            acc += __expf(sc[r] - m) * inv * rev[r * 129 + tid];
        if (set == 0) {
            acc += pf[0] * q_emb[b * D + tid];
            out[b * D + tid] = acc;
        } else {
            out[NB * D + b * D + tid] = acc;
        }
    }
}

extern "C" void kernel_launch(void* const* d_in, const int* in_sizes, int n_in,
                              void* d_out, int out_size, void* d_ws, size_t ws_size,
                              hipStream_t stream) {
    const int*   user_w  = (const int*)d_in[0];
    const int*   item_w  = (const int*)d_in[1];
    const int*   query_w = (const int*)d_in[2];
    const float* emb     = (const float*)d_in[3];
    const float* w_self  = (const float*)d_in[4];
    const float* b_self  = (const float*)d_in[5];
    const float* Wq      = (const float*)d_in[6];
    const float* bq      = (const float*)d_in[7];
    const float* w_red   = (const float*)d_in[8];
    const float* pf      = (const float*)d_in[9];

    float* ws       = (float*)d_ws;
    float* user_emb = ws;                          // 5120*128
    float* item_emb = user_emb + NDOC_UI * D;      // 5120*128
    float* q_emb    = item_emb + NDOC_UI * D;      // 256*128
    float* pv       = q_emb    + NB * D;           // 256*128
    float* evocab   = pv       + NB * D;           // 50000
    ushort* emb_bf  = (ushort*)(evocab + VOCAB);   // 50000*128 bf16 = 12.8 MB
    float* out      = (float*)d_out;

    // Fast path needs the bf16 vocab table in ws; guard against small ws.
    const size_t need_fast =
        (size_t)(2 * NDOC_UI * D + 2 * NB * D + VOCAB) * sizeof(float)
        + (size_t)VOCAB * D * sizeof(ushort);      // 18,505,024 B

    if (ws_size >= need_fast) {
        vocab_prep_kernel<<<VOCAB / 8, 256, 0, stream>>>(
            emb, w_self, b_self, emb_bf, evocab);
        doc_embed_bf16_kernel<<<(2 * NDOC_UI + NB) / 8, 256, 0, stream>>>(
            user_w, item_w, query_w, emb_bf, evocab, user_emb, item_emb, q_emb);
    } else {
        doc_embed_fp32_kernel<<<(2 * NDOC_UI + NB) / 8, 256, 0, stream>>>(
            user_w, item_w, query_w, emb, w_self, b_self, user_emb, item_emb, q_emb);
    }
    pv_kernel<<<dim3(128, 4), 256, 0, stream>>>(q_emb, Wq, bq, w_red, pv);
    attn_kernel<<<dim3(NB, 2), 256, 0, stream>>>(user_emb, item_emb, q_emb, pv, pf, out);
}